// Round 18
// baseline (6999.555 us; speedup 1.0000x reference)
//
#include <hip/hip_runtime.h>

// CustomGRU: B=256, T=1024, I=128, H=256.  out = concat(output[B,T,H], h_last[B,H]) f32.
//
// R18 = R16 compute shape, halved WGs for cross-WG latency hiding:
// 512 WGs x 256 thr (2 WGs/CU). Group = 8 WGs x 32 units, 4 batches; group id
// g = ((bid>>6)<<3)|(bid&7) makes members one contiguous 64-bid block (same XCD
// residue, co-launched) while CU-cohabitants (bid+-256) are DIFFERENT groups ->
// when one WG stalls on its exchange RTT, the other's waves issue (R17 showed
// intra-WG phase-splitting cannot hide the stall; only independent waves can).
// Per-thread: 4 units x 8-k slice, 96 pinned W f32, 192 pk_fma, R16 reduce chain,
// packed-u64 parity exchange. Benign failure: if 2/CU residency fails, groups
// complete block-sequentially (dur ~= R16, no hang).

#define B_SZ 256
#define T_SZ 1024
#define H_SZ 256
#define G3   768
#define NGRP 64
#define SPIN_MAX (1 << 21)
#define HROW 288

typedef __attribute__((ext_vector_type(2))) float f32x2;

template<int CTRL>
__device__ __forceinline__ float dppx(float s) {
    return __int_as_float(
        __builtin_amdgcn_update_dpp(0, __float_as_int(s), CTRL, 0xF, 0xF, true));
}
template<int MASK>
__device__ __forceinline__ float swzx(float s) {
    return __int_as_float(__builtin_amdgcn_ds_swizzle(__float_as_int(s), MASK));
}
__device__ __forceinline__ f32x2 pkfma(f32x2 a, f32x2 b, f32x2 c) {
    f32x2 d;
    asm("v_pk_fma_f32 %0, %1, %2, %3" : "=v"(d) : "v"(a), "v"(b), "v"(c));
    return d;
}

// h position map: word k -> k + 4*(k>>5)  (injective; 4-word pad per 32 words)
static __device__ __forceinline__ int hpos(int k) { return k + 4 * (k >> 5); }

// slot: [g 64][par 2][n 4][unit 256] u64 = (ver<<32)|f32bits
static __device__ __forceinline__ size_t xsl(int g, int par, int n, int u) {
    return (((size_t)g * 2 + par) * 4 + n) * 256 + u;
}

// ---------------- prep ----------------
__global__ void prep_kernel(const float* __restrict__ h0,
                            unsigned long long* __restrict__ xch) {
    int tid = blockIdx.x * blockDim.x + threadIdx.x;
    if (tid < B_SZ * H_SZ) {
        int b = tid >> 8, u = tid & 255;
        int g = b >> 2, n = b & 3;
        unsigned long long val = (unsigned long long)__float_as_uint(h0[tid]);
        xch[xsl(g, 0, n, u)] = val;
        xch[xsl(g, 1, n, u)] = val;
    }
}

// ---------------- phase 1: gx = x @ W_ih^T (unchanged since R9) ----------------
__global__ __launch_bounds__(256) void gemm_x_kernel(
    const float* __restrict__ x, const float* __restrict__ wih,
    float* __restrict__ gx, int c, int tcShift)
{
    __shared__ __align__(16) float xs[64][132];
    __shared__ __align__(16) float ws[128][68];
    const int TC = 1 << tcShift;
    const int t  = threadIdx.x;
    const int bx = blockIdx.x, by = blockIdx.y;

#pragma unroll
    for (int i = 0; i < 8; ++i) {
        int f4 = t + i * 256;
        int r  = f4 >> 5, c4 = (f4 & 31) * 4;
        int rho = bx * 64 + r;
        int b = rho >> tcShift, u = rho & (TC - 1);
        float4 v = *(const float4*)(x + ((size_t)b * T_SZ + (size_t)c * TC + u) * 128 + c4);
        *(float4*)&xs[r][c4] = v;
    }

    const int gl = t & 31;
    const int rl = t >> 5;
    float acc[8][4];
#pragma unroll
    for (int i = 0; i < 8; ++i)
#pragma unroll
        for (int jj = 0; jj < 4; ++jj) acc[i][jj] = 0.f;

    for (int kb = 0; kb < 2; ++kb) {
        __syncthreads();
#pragma unroll
        for (int i = 0; i < 8; ++i) {
            int f4 = t + i * 256;
            int row = f4 >> 4, c4 = (f4 & 15) * 4;
            float4 v = *(const float4*)(wih + (size_t)(by * 128 + row) * 128 + kb * 64 + c4);
            *(float4*)&ws[row][c4] = v;
        }
        __syncthreads();

#pragma unroll 4
        for (int k4 = 0; k4 < 16; ++k4) {
            float4 wv0 = *(const float4*)&ws[gl     ][k4 * 4];
            float4 wv1 = *(const float4*)&ws[gl + 32][k4 * 4];
            float4 wv2 = *(const float4*)&ws[gl + 64][k4 * 4];
            float4 wv3 = *(const float4*)&ws[gl + 96][k4 * 4];
#pragma unroll
            for (int rr = 0; rr < 8; ++rr) {
                float4 xv = *(const float4*)&xs[rl + rr * 8][kb * 64 + k4 * 4];
                acc[rr][0] = fmaf(xv.w, wv0.w, fmaf(xv.z, wv0.z, fmaf(xv.y, wv0.y, fmaf(xv.x, wv0.x, acc[rr][0]))));
                acc[rr][1] = fmaf(xv.w, wv1.w, fmaf(xv.z, wv1.z, fmaf(xv.y, wv1.y, fmaf(xv.x, wv1.x, acc[rr][1]))));
                acc[rr][2] = fmaf(xv.w, wv2.w, fmaf(xv.z, wv2.z, fmaf(xv.y, wv2.y, fmaf(xv.x, wv2.x, acc[rr][2]))));
                acc[rr][3] = fmaf(xv.w, wv3.w, fmaf(xv.z, wv3.z, fmaf(xv.y, wv3.y, fmaf(xv.x, wv3.x, acc[rr][3]))));
            }
        }
    }

#pragma unroll
    for (int rr = 0; rr < 8; ++rr) {
        size_t base = (size_t)(bx * 64 + rl + rr * 8) * G3 + by * 128 + gl;
#pragma unroll
        for (int gi = 0; gi < 4; ++gi)
            gx[base + 32 * gi] = acc[rr][gi];
    }
}

#define PIN2(v) asm volatile("" : "+v"(v));

// ---------------- phase 2: recurrence ----------------
// grid 512 x 256. g = ((bid>>6)<<3)|(bid&7), m = (bid>>3)&7, u0 = 32m.
// Thread: q = t>>5 (unit quad uq = u0+4q, q 0..7), p = t&31 (8-k slice), pb = p&3.
// fam = gate*4 + e. s[fam][i] = batch i^pb partial (R16 reduce chain).
__global__ __launch_bounds__(256)
__attribute__((amdgpu_waves_per_eu(2, 2)))
void gru_kernel(
    const float* __restrict__ gx, const float* __restrict__ whh,
    const float* __restrict__ bih, const float* __restrict__ bhh,
    unsigned long long* __restrict__ xch, float* __restrict__ out,
    int gbase, int tc, int isLast)
{
    __shared__ __align__(16) float hl[4][HROW];
    __shared__ __align__(16) float hst[4][32];

    const int t   = threadIdx.x;
    const int bid = blockIdx.x;
    const int g   = ((bid >> 6) << 3) | (bid & 7);
    const int m   = (bid >> 3) & 7;
    const int u0  = m * 32;
    const int q   = t >> 5;
    const int p   = t & 31;
    const int pb  = p & 3;
    const int uq  = u0 + 4 * q;
    const int k0  = 8 * p;

    // ---- W: 12 fams (3 gates x 4 units) x 8 k = 48 pinned f32x2 ----
    f32x2 wf[12][4];
#pragma unroll
    for (int gate = 0; gate < 3; ++gate) {
#pragma unroll
        for (int e = 0; e < 4; ++e) {
            const float* wr = whh + (size_t)(gate * 256 + uq + e) * H_SZ + k0;
            float4 va = *(const float4*)(wr);
            float4 vb = *(const float4*)(wr + 4);
            wf[gate * 4 + e][0] = (f32x2){va.x, va.y};
            wf[gate * 4 + e][1] = (f32x2){va.z, va.w};
            wf[gate * 4 + e][2] = (f32x2){vb.x, vb.y};
            wf[gate * 4 + e][3] = (f32x2){vb.z, vb.w};
        }
    }
#pragma unroll
    for (int f = 0; f < 12; ++f) {
        PIN2(wf[f][0]) PIN2(wf[f][1]) PIN2(wf[f][2]) PIN2(wf[f][3])
    }

    // ---- gate-lane invariants: lanes p<4 (units uq,uq+1), p in 16..19 (uq+2,uq+3) ----
    const bool hi  = (p >= 16);
    const bool act = (p < 4) || (p >= 16 && p < 20);
    const int  ueA = uq + (hi ? 2 : 0);
    float bsrA = 0.f, bszA = 0.f, bsnA = 0.f, bsrB = 0.f, bszB = 0.f, bsnB = 0.f;
    const float* gxp = nullptr;
    if (act) {
        bsrA = bih[ueA]       + bhh[ueA];
        bszA = bih[256 + ueA] + bhh[256 + ueA];
        bsnA = bih[512 + ueA] + bhh[512 + ueA];
        bsrB = bih[ueA + 1]   + bhh[ueA + 1];
        bszB = bih[257 + ueA] + bhh[257 + ueA];
        bsnB = bih[513 + ueA] + bhh[513 + ueA];
        gxp = gx + ((size_t)(4 * g + pb) * tc) * G3 + ueA;
    }

    // gather mapping: thread polls 4 slots (batch n_t, units 4c..4c+3)
    const int n_t  = t >> 6;
    const int c_t  = t & 63;
    const int wofs = 4 * c_t + 4 * (c_t >> 3);   // = hpos(4*c_t)
    // matvec row pointers, hoisted
    const int Wd = hpos(k0);
    const float* hrow[4];
#pragma unroll
    for (int i = 0; i < 4; ++i) hrow[i] = &hl[i ^ pb][Wd];
    const int pua = hpos(ueA);
    // out-store mapping (t<32)
    const int n_o = t >> 3, f_o = t & 7;

    // preload gx(u=0)
    float gxrA = 0.f, gxzA = 0.f, gxnA = 0.f, gxrB = 0.f, gxzB = 0.f, gxnB = 0.f;
    if (act) {
        gxrA = gxp[0]; gxzA = gxp[256]; gxnA = gxp[512];
        gxrB = gxp[1]; gxzB = gxp[257]; gxnB = gxp[513];
    }

#pragma unroll 1
    for (int u = 0; u < tc; ++u) {
        const int tg  = gbase + u;
        const int par = tg & 1;

        // ---- coalesced out-store for step u-1 ----
        if (u > 0 && t < 32) {
            float4 o;
            o.x = hst[n_o][4 * f_o];     o.y = hst[n_o][4 * f_o + 1];
            o.z = hst[n_o][4 * f_o + 2]; o.w = hst[n_o][4 * f_o + 3];
            *(float4*)(out + ((size_t)(4 * g + n_o) * T_SZ + (tg - 1)) * H_SZ + u0 + 4 * f_o) = o;
        }

        // ---- gather h(tg): poll 4 packed slots ----
        {
            unsigned long long* sb = xch + xsl(g, par, n_t, 4 * c_t);
            const unsigned want = (unsigned)tg;
            unsigned long long v0, v1, v2, v3;
            int sp = 0;
            for (;;) {
                v0 = __hip_atomic_load(sb + 0, __ATOMIC_RELAXED, __HIP_MEMORY_SCOPE_AGENT);
                v1 = __hip_atomic_load(sb + 1, __ATOMIC_RELAXED, __HIP_MEMORY_SCOPE_AGENT);
                v2 = __hip_atomic_load(sb + 2, __ATOMIC_RELAXED, __HIP_MEMORY_SCOPE_AGENT);
                v3 = __hip_atomic_load(sb + 3, __ATOMIC_RELAXED, __HIP_MEMORY_SCOPE_AGENT);
                bool ok = ((unsigned)(v0 >> 32) == want) & ((unsigned)(v1 >> 32) == want) &
                          ((unsigned)(v2 >> 32) == want) & ((unsigned)(v3 >> 32) == want);
                if (ok || ++sp >= SPIN_MAX) break;
                __builtin_amdgcn_s_sleep(1);
            }
            float4 hv;
            hv.x = __uint_as_float((unsigned)v0);
            hv.y = __uint_as_float((unsigned)v1);
            hv.z = __uint_as_float((unsigned)v2);
            hv.w = __uint_as_float((unsigned)v3);
            *(float4*)&hl[n_t][wofs] = hv;
        }
        __syncthreads();

        // ---- prefetch gx(u+1) ----
        float pgrA = 0.f, pgzA = 0.f, pgnA = 0.f, pgrB = 0.f, pgzB = 0.f, pgnB = 0.f;
        if (act && u + 1 < tc) {
            size_t go = (size_t)(u + 1) * G3;
            pgrA = gxp[go];     pgzA = gxp[go + 256]; pgnA = gxp[go + 512];
            pgrB = gxp[go + 1]; pgzB = gxp[go + 257]; pgnB = gxp[go + 513];
        }

        // ---- matvec: 8 b128 reads, 192 pk_fma ----
        float s[12][4];
#pragma unroll
        for (int i = 0; i < 4; ++i) {
            const float* hr = hrow[i];
            float4 hv0 = *(const float4*)(hr);
            float4 hv1 = *(const float4*)(hr + 4);
            f32x2 h0 = (f32x2){hv0.x, hv0.y};
            f32x2 h1 = (f32x2){hv0.z, hv0.w};
            f32x2 h2 = (f32x2){hv1.x, hv1.y};
            f32x2 h3 = (f32x2){hv1.z, hv1.w};
            f32x2 z  = (f32x2){0.f, 0.f};
#pragma unroll
            for (int f = 0; f < 12; ++f) {
                f32x2 a = pkfma(h0, wf[f][0],
                          pkfma(h1, wf[f][1],
                          pkfma(h2, wf[f][2],
                          pkfma(h3, wf[f][3], z))));
                s[f][i] = a.x + a.y;
            }
        }

        // ---- reduce: xor1,xor2 (dpp select) | ror4+ror8 (dpp coset) | xor16 (swz) ----
#pragma unroll
        for (int f = 0; f < 12; ++f) {
            s[f][0] += dppx<0xB1>(s[f][1]);
            s[f][2] += dppx<0xB1>(s[f][3]);
            s[f][0] += dppx<0x4E>(s[f][2]);
            s[f][0] += dppx<0x124>(s[f][0]);   // ror4
            s[f][0] += dppx<0x128>(s[f][0]);   // ror8
            s[f][0] += swzx<0x401F>(s[f][0]);  // xor16
        }

        // ---- gates + publish (active lanes: batch pb, units ueA, ueA+1) ----
        if (act) {
            float srA = hi ? s[2][0]  : s[0][0];
            float srB = hi ? s[3][0]  : s[1][0];
            float szA = hi ? s[6][0]  : s[4][0];
            float szB = hi ? s[7][0]  : s[5][0];
            float snA = hi ? s[10][0] : s[8][0];
            float snB = hi ? s[11][0] : s[9][0];

            float holdA = hl[pb][pua];
            float holdB = hl[pb][pua + 1];
            float arA = srA + gxrA + bsrA;
            float azA = szA + gxzA + bszA;
            float anA = snA + gxnA + bsnA;
            float arB = srB + gxrB + bsrB;
            float azB = szB + gxzB + bszB;
            float anB = snB + gxnB + bsnB;
            float rA = 1.f / (1.f + expf(-arA));
            float zA = 1.f / (1.f + expf(-azA));
            float nA = tanhf(rA * anA);
            float rB = 1.f / (1.f + expf(-arB));
            float zB = 1.f / (1.f + expf(-azB));
            float nB = tanhf(rB * anB);
            float hnA = (1.f - zA) * holdA + zA * nA;
            float hnB = (1.f - zB) * holdB + zB * nB;

            hst[pb][ueA - u0]     = hnA;
            hst[pb][ueA - u0 + 1] = hnB;
            const unsigned long long ver = (unsigned long long)(unsigned)(tg + 1) << 32;
            const int par1 = (tg + 1) & 1;
            __hip_atomic_store(xch + xsl(g, par1, pb, ueA),
                               ver | (unsigned long long)__float_as_uint(hnA),
                               __ATOMIC_RELAXED, __HIP_MEMORY_SCOPE_AGENT);
            __hip_atomic_store(xch + xsl(g, par1, pb, ueA + 1),
                               ver | (unsigned long long)__float_as_uint(hnB),
                               __ATOMIC_RELAXED, __HIP_MEMORY_SCOPE_AGENT);
        }
        gxrA = pgrA; gxzA = pgzA; gxnA = pgnA;
        gxrB = pgrB; gxzB = pgzB; gxnB = pgnB;
        __syncthreads();   // hl reads done; hst visible; publishes drained
    }

    // ---- flush last step's out row (+ h_last) ----
    if (t < 32) {
        float4 o;
        o.x = hst[n_o][4 * f_o];     o.y = hst[n_o][4 * f_o + 1];
        o.z = hst[n_o][4 * f_o + 2]; o.w = hst[n_o][4 * f_o + 3];
        *(float4*)(out + ((size_t)(4 * g + n_o) * T_SZ + (gbase + tc - 1)) * H_SZ + u0 + 4 * f_o) = o;
        if (isLast)
            *(float4*)(out + (size_t)B_SZ * T_SZ * H_SZ
                           + (size_t)(4 * g + n_o) * H_SZ + u0 + 4 * f_o) = o;
    }
}

// ---------------- host ----------------
extern "C" void kernel_launch(void* const* d_in, const int* in_sizes, int n_in,
                              void* d_out, int out_size, void* d_ws, size_t ws_size,
                              hipStream_t stream) {
    const float* x   = (const float*)d_in[0];
    const float* h0  = (const float*)d_in[1];
    const float* wih = (const float*)d_in[2];
    const float* whh = (const float*)d_in[3];
    const float* bih = (const float*)d_in[4];
    const float* bhh = (const float*)d_in[5];
    float* out = (float*)d_out;

    char* ws = (char*)d_ws;
    const size_t xchB = (size_t)NGRP * 2 * 4 * 256 * 8;   // 512 KiB
    unsigned long long* xch = (unsigned long long*)ws;
    float* gxb = (float*)(ws + xchB);

    int tcShift = 10;
    while (tcShift > 0 &&
           xchB + (786432ull << tcShift) > ws_size) --tcShift;
    const int TC  = 1 << tcShift;
    const int nCh = T_SZ / TC;

    prep_kernel<<<dim3(256), dim3(256), 0, stream>>>(h0, xch);
    for (int c = 0; c < nCh; ++c) {
        gemm_x_kernel<<<dim3(B_SZ * TC / 64, 6), dim3(256), 0, stream>>>(
            x, wih, gxb, c, tcShift);
        gru_kernel<<<dim3(512), dim3(256), 0, stream>>>(
            gxb, whh, bih, bhh, xch, out, c * TC, TC, (c == nCh - 1) ? 1 : 0);
    }
}

// Round 19
// 3712.246 us; speedup vs baseline: 1.8855x; 1.8855x over previous
//
#include <hip/hip_runtime.h>

// CustomGRU: B=256, T=1024, I=128, H=256.  out = concat(output[B,T,H], h_last[B,H]) f32.
//
// R19 = R16 base (64 groups x 4 WGs x 512 thr, 4 units x 8k/thread, 96 pinned W f32,
// packed-u64 parity exchange) + two overhead cuts:
//  1. ONE barrier/step (was 2): hl/hst parity-double-buffered; the single barrier
//     sits between gather-writes and matvec-reads. Publish-drain now overlaps the
//     next step's out-store+poll. Protocol safety is barrier-independent (publish
//     of tg+1 follows gather(tg) in program order through the barrier).
//  2. Gates spread over 16 lanes x 1 unit (was 8 x 2): halves the serial
//     transcendental chain.

#define B_SZ 256
#define T_SZ 1024
#define H_SZ 256
#define G3   768
#define NGRP 64
#define SPIN_MAX (1 << 21)
#define HROW 288

typedef __attribute__((ext_vector_type(2))) float f32x2;

template<int CTRL>
__device__ __forceinline__ float dppx(float s) {
    return __int_as_float(
        __builtin_amdgcn_update_dpp(0, __float_as_int(s), CTRL, 0xF, 0xF, true));
}
template<int MASK>
__device__ __forceinline__ float swzx(float s) {
    return __int_as_float(__builtin_amdgcn_ds_swizzle(__float_as_int(s), MASK));
}
__device__ __forceinline__ f32x2 pkfma(f32x2 a, f32x2 b, f32x2 c) {
    f32x2 d;
    asm("v_pk_fma_f32 %0, %1, %2, %3" : "=v"(d) : "v"(a), "v"(b), "v"(c));
    return d;
}

// h position map: word k -> k + 4*(k>>5)  (injective; 4-word pad per 32 words)
static __device__ __forceinline__ int hpos(int k) { return k + 4 * (k >> 5); }

// slot: [g 64][par 2][n 4][unit 256] u64 = (ver<<32)|f32bits
static __device__ __forceinline__ size_t xsl(int g, int par, int n, int u) {
    return (((size_t)g * 2 + par) * 4 + n) * 256 + u;
}

// ---------------- prep ----------------
__global__ void prep_kernel(const float* __restrict__ h0,
                            unsigned long long* __restrict__ xch) {
    int tid = blockIdx.x * blockDim.x + threadIdx.x;
    if (tid < B_SZ * H_SZ) {
        int b = tid >> 8, u = tid & 255;
        int g = b >> 2, n = b & 3;
        unsigned long long val = (unsigned long long)__float_as_uint(h0[tid]);
        xch[xsl(g, 0, n, u)] = val;
        xch[xsl(g, 1, n, u)] = val;
    }
}

// ---------------- phase 1: gx = x @ W_ih^T (unchanged since R9) ----------------
__global__ __launch_bounds__(256) void gemm_x_kernel(
    const float* __restrict__ x, const float* __restrict__ wih,
    float* __restrict__ gx, int c, int tcShift)
{
    __shared__ __align__(16) float xs[64][132];
    __shared__ __align__(16) float ws[128][68];
    const int TC = 1 << tcShift;
    const int t  = threadIdx.x;
    const int bx = blockIdx.x, by = blockIdx.y;

#pragma unroll
    for (int i = 0; i < 8; ++i) {
        int f4 = t + i * 256;
        int r  = f4 >> 5, c4 = (f4 & 31) * 4;
        int rho = bx * 64 + r;
        int b = rho >> tcShift, u = rho & (TC - 1);
        float4 v = *(const float4*)(x + ((size_t)b * T_SZ + (size_t)c * TC + u) * 128 + c4);
        *(float4*)&xs[r][c4] = v;
    }

    const int gl = t & 31;
    const int rl = t >> 5;
    float acc[8][4];
#pragma unroll
    for (int i = 0; i < 8; ++i)
#pragma unroll
        for (int jj = 0; jj < 4; ++jj) acc[i][jj] = 0.f;

    for (int kb = 0; kb < 2; ++kb) {
        __syncthreads();
#pragma unroll
        for (int i = 0; i < 8; ++i) {
            int f4 = t + i * 256;
            int row = f4 >> 4, c4 = (f4 & 15) * 4;
            float4 v = *(const float4*)(wih + (size_t)(by * 128 + row) * 128 + kb * 64 + c4);
            *(float4*)&ws[row][c4] = v;
        }
        __syncthreads();

#pragma unroll 4
        for (int k4 = 0; k4 < 16; ++k4) {
            float4 wv0 = *(const float4*)&ws[gl     ][k4 * 4];
            float4 wv1 = *(const float4*)&ws[gl + 32][k4 * 4];
            float4 wv2 = *(const float4*)&ws[gl + 64][k4 * 4];
            float4 wv3 = *(const float4*)&ws[gl + 96][k4 * 4];
#pragma unroll
            for (int rr = 0; rr < 8; ++rr) {
                float4 xv = *(const float4*)&xs[rl + rr * 8][kb * 64 + k4 * 4];
                acc[rr][0] = fmaf(xv.w, wv0.w, fmaf(xv.z, wv0.z, fmaf(xv.y, wv0.y, fmaf(xv.x, wv0.x, acc[rr][0]))));
                acc[rr][1] = fmaf(xv.w, wv1.w, fmaf(xv.z, wv1.z, fmaf(xv.y, wv1.y, fmaf(xv.x, wv1.x, acc[rr][1]))));
                acc[rr][2] = fmaf(xv.w, wv2.w, fmaf(xv.z, wv2.z, fmaf(xv.y, wv2.y, fmaf(xv.x, wv2.x, acc[rr][2]))));
                acc[rr][3] = fmaf(xv.w, wv3.w, fmaf(xv.z, wv3.z, fmaf(xv.y, wv3.y, fmaf(xv.x, wv3.x, acc[rr][3]))));
            }
        }
    }

#pragma unroll
    for (int rr = 0; rr < 8; ++rr) {
        size_t base = (size_t)(bx * 64 + rl + rr * 8) * G3 + by * 128 + gl;
#pragma unroll
        for (int gi = 0; gi < 4; ++gi)
            gx[base + 32 * gi] = acc[rr][gi];
    }
}

#define PIN2(v) asm volatile("" : "+v"(v));

// ---------------- phase 2: recurrence ----------------
// grid 256 x 512. g = bid&63, m = bid>>6 (same XCD members), u0 = 64m.
// Thread: q = t>>5 (quad uq = u0+4q), p = t&31 (8-k slice), pb = p&3.
// fam = gate*4 + e. After reduce: lane p holds batch pb sums for all 12 fams.
// Gates: lanes p<16, one (batch pb, unit uq + ((p>>2)&3)) each.
__global__ __launch_bounds__(512)
__attribute__((amdgpu_waves_per_eu(2, 2)))
void gru_kernel(
    const float* __restrict__ gx, const float* __restrict__ whh,
    const float* __restrict__ bih, const float* __restrict__ bhh,
    unsigned long long* __restrict__ xch, float* __restrict__ out,
    int gbase, int tc, int isLast)
{
    __shared__ __align__(16) float hl[2][4][HROW];
    __shared__ __align__(16) float hst[2][4][64];

    const int t   = threadIdx.x;
    const int bid = blockIdx.x;
    const int g   = bid & 63;
    const int m   = bid >> 6;
    const int u0  = m * 64;
    const int q   = t >> 5;
    const int p   = t & 31;
    const int pb  = p & 3;
    const int uq  = u0 + 4 * q;
    const int k0  = 8 * p;

    // ---- W: 12 fams (3 gates x 4 units) x 8 k = 48 pinned f32x2 ----
    f32x2 wf[12][4];
#pragma unroll
    for (int gate = 0; gate < 3; ++gate) {
#pragma unroll
        for (int e = 0; e < 4; ++e) {
            const float* wr = whh + (size_t)(gate * 256 + uq + e) * H_SZ + k0;
            float4 va = *(const float4*)(wr);
            float4 vb = *(const float4*)(wr + 4);
            wf[gate * 4 + e][0] = (f32x2){va.x, va.y};
            wf[gate * 4 + e][1] = (f32x2){va.z, va.w};
            wf[gate * 4 + e][2] = (f32x2){vb.x, vb.y};
            wf[gate * 4 + e][3] = (f32x2){vb.z, vb.w};
        }
    }
#pragma unroll
    for (int f = 0; f < 12; ++f) {
        PIN2(wf[f][0]) PIN2(wf[f][1]) PIN2(wf[f][2]) PIN2(wf[f][3])
    }

    // ---- gate-lane invariants: lanes p<16; e = (p>>2)&3, unit ue = uq+e ----
    const bool act = (p < 16);
    const int  e   = (p >> 2) & 3;
    const int  ue  = uq + e;
    float bsr = 0.f, bsz = 0.f, bsn = 0.f;
    const float* gxp = nullptr;
    if (act) {
        bsr = bih[ue]       + bhh[ue];
        bsz = bih[256 + ue] + bhh[256 + ue];
        bsn = bih[512 + ue] + bhh[512 + ue];
        gxp = gx + ((size_t)(4 * g + pb) * tc) * G3 + ue;
    }

    // gather mapping: thread polls 2 slots (batch n_t, units 2c2, 2c2+1)
    const int n_t  = t >> 7;
    const int c2   = t & 127;
    const int wofs = 2 * c2 + 4 * (c2 >> 4);     // = hpos(2*c2)
    // matvec row base offsets (row i^pb), per parity buffer
    const int Wd = hpos(k0);
    const int pue = hpos(ue);
    // out-store mapping (t<64)
    const int n_o = t >> 4, f_o = t & 15;

    // preload gx(u=0)
    float gxr = 0.f, gxz = 0.f, gxn = 0.f;
    if (act) { gxr = gxp[0]; gxz = gxp[256]; gxn = gxp[512]; }

#pragma unroll 1
    for (int u = 0; u < tc; ++u) {
        const int tg   = gbase + u;
        const int par  = tg & 1;
        const int par1 = (tg + 1) & 1;

        // ---- gather h(tg) into hl[par] (packed slots: data arrives with version) ----
        {
            unsigned long long* sb = xch + xsl(g, par, n_t, 2 * c2);
            const unsigned want = (unsigned)tg;
            unsigned long long v0, v1;
            int sp = 0;
            for (;;) {
                v0 = __hip_atomic_load(sb + 0, __ATOMIC_RELAXED, __HIP_MEMORY_SCOPE_AGENT);
                v1 = __hip_atomic_load(sb + 1, __ATOMIC_RELAXED, __HIP_MEMORY_SCOPE_AGENT);
                bool ok = ((unsigned)(v0 >> 32) == want) & ((unsigned)(v1 >> 32) == want);
                if (ok || ++sp >= SPIN_MAX) break;
                __builtin_amdgcn_s_sleep(1);
            }
            float2 hv;
            hv.x = __uint_as_float((unsigned)v0);
            hv.y = __uint_as_float((unsigned)v1);
            *(float2*)&hl[par][n_t][wofs] = hv;
        }
        __syncthreads();   // the ONE barrier: hl[par] visible; also orders hst/hl reuse

        // ---- coalesced out-store for step u-1 (from hst[par^1]) ----
        if (u > 0 && t < 64) {
            float4 o;
            o.x = hst[par1][n_o][4 * f_o];     o.y = hst[par1][n_o][4 * f_o + 1];
            o.z = hst[par1][n_o][4 * f_o + 2]; o.w = hst[par1][n_o][4 * f_o + 3];
            *(float4*)(out + ((size_t)(4 * g + n_o) * T_SZ + (tg - 1)) * H_SZ + u0 + 4 * f_o) = o;
        }

        // ---- prefetch gx(u+1) ----
        float pgr = 0.f, pgz = 0.f, pgn = 0.f;
        if (act && u + 1 < tc) {
            size_t go = (size_t)(u + 1) * G3;
            pgr = gxp[go]; pgz = gxp[go + 256]; pgn = gxp[go + 512];
        }

        // ---- matvec: 8 b128 reads of hl[par], 192 pk_fma ----
        float s[12][4];
        {
            const float* hb = &hl[par][0][0] + Wd;
#pragma unroll
            for (int i = 0; i < 4; ++i) {
                const float* hr = hb + (size_t)(i ^ pb) * HROW;
                float4 hv0 = *(const float4*)(hr);
                float4 hv1 = *(const float4*)(hr + 4);
                f32x2 h0 = (f32x2){hv0.x, hv0.y};
                f32x2 h1 = (f32x2){hv0.z, hv0.w};
                f32x2 h2 = (f32x2){hv1.x, hv1.y};
                f32x2 h3 = (f32x2){hv1.z, hv1.w};
                f32x2 z  = (f32x2){0.f, 0.f};
#pragma unroll
                for (int f = 0; f < 12; ++f) {
                    f32x2 a = pkfma(h0, wf[f][0],
                              pkfma(h1, wf[f][1],
                              pkfma(h2, wf[f][2],
                              pkfma(h3, wf[f][3], z))));
                    s[f][i] = a.x + a.y;
                }
            }
        }

        // ---- reduce: xor1,xor2 (dpp select) | ror4+ror8 (dpp coset) | xor16 (swz) ----
#pragma unroll
        for (int f = 0; f < 12; ++f) {
            s[f][0] += dppx<0xB1>(s[f][1]);
            s[f][2] += dppx<0xB1>(s[f][3]);
            s[f][0] += dppx<0x4E>(s[f][2]);
            s[f][0] += dppx<0x124>(s[f][0]);   // ror4
            s[f][0] += dppx<0x128>(s[f][0]);   // ror8
            s[f][0] += swzx<0x401F>(s[f][0]);  // xor16
        }

        // ---- gates + publish (lanes p<16: batch pb, unit ue) ----
        if (act) {
            float sr = (e & 2) ? ((e & 1) ? s[3][0]  : s[2][0])
                               : ((e & 1) ? s[1][0]  : s[0][0]);
            float sz = (e & 2) ? ((e & 1) ? s[7][0]  : s[6][0])
                               : ((e & 1) ? s[5][0]  : s[4][0]);
            float sn = (e & 2) ? ((e & 1) ? s[11][0] : s[10][0])
                               : ((e & 1) ? s[9][0]  : s[8][0]);

            float hold = hl[par][pb][pue];
            float ar = sr + gxr + bsr;
            float az = sz + gxz + bsz;
            float an = sn + gxn + bsn;
            float r  = 1.f / (1.f + expf(-ar));
            float z  = 1.f / (1.f + expf(-az));
            float nn = tanhf(r * an);
            float hn = (1.f - z) * hold + z * nn;

            hst[par][pb][ue - u0] = hn;
            __hip_atomic_store(xch + xsl(g, par1, pb, ue),
                               ((unsigned long long)(unsigned)(tg + 1) << 32) |
                               (unsigned long long)__float_as_uint(hn),
                               __ATOMIC_RELAXED, __HIP_MEMORY_SCOPE_AGENT);
        }
        gxr = pgr; gxz = pgz; gxn = pgn;
        // no end barrier: next step's barrier provides all orderings
    }

    // ---- flush last step's out row (+ h_last) ----
    __syncthreads();
    {
        const int fpar = (gbase + tc - 1) & 1;
        if (t < 64) {
            float4 o;
            o.x = hst[fpar][n_o][4 * f_o];     o.y = hst[fpar][n_o][4 * f_o + 1];
            o.z = hst[fpar][n_o][4 * f_o + 2]; o.w = hst[fpar][n_o][4 * f_o + 3];
            *(float4*)(out + ((size_t)(4 * g + n_o) * T_SZ + (gbase + tc - 1)) * H_SZ + u0 + 4 * f_o) = o;
            if (isLast)
                *(float4*)(out + (size_t)B_SZ * T_SZ * H_SZ
                               + (size_t)(4 * g + n_o) * H_SZ + u0 + 4 * f_o) = o;
        }
    }
}

// ---------------- host ----------------
extern "C" void kernel_launch(void* const* d_in, const int* in_sizes, int n_in,
                              void* d_out, int out_size, void* d_ws, size_t ws_size,
                              hipStream_t stream) {
    const float* x   = (const float*)d_in[0];
    const float* h0  = (const float*)d_in[1];
    const float* wih = (const float*)d_in[2];
    const float* whh = (const float*)d_in[3];
    const float* bih = (const float*)d_in[4];
    const float* bhh = (const float*)d_in[5];
    float* out = (float*)d_out;

    char* ws = (char*)d_ws;
    const size_t xchB = (size_t)NGRP * 2 * 4 * 256 * 8;   // 512 KiB
    unsigned long long* xch = (unsigned long long*)ws;
    float* gxb = (float*)(ws + xchB);

    int tcShift = 10;
    while (tcShift > 0 &&
           xchB + (786432ull << tcShift) > ws_size) --tcShift;
    const int TC  = 1 << tcShift;
    const int nCh = T_SZ / TC;

    prep_kernel<<<dim3(256), dim3(256), 0, stream>>>(h0, xch);
    for (int c = 0; c < nCh; ++c) {
        gemm_x_kernel<<<dim3(B_SZ * TC / 64, 6), dim3(256), 0, stream>>>(
            x, wih, gxb, c, tcShift);
        gru_kernel<<<dim3(B_SZ), dim3(512), 0, stream>>>(
            gxb, whh, bih, bhh, xch, out, c * TC, TC, (c == nCh - 1) ? 1 : 0);
    }
}